// Round 1
// baseline (1365.386 us; speedup 1.0000x reference)
//
#include <hip/hip_runtime.h>

#define N_NODES 100000
#define N_EDGES 3200000
#define D_IN    512
#define D_OUT   256

// ---------------------------------------------------------------------------
// GEMM: xw[N,256] = x[N,512] @ W[512,256], fp32 VALU, 128x128 tile, 8x8 micro
// ---------------------------------------------------------------------------
#define TM 128
#define TN 128
#define TK 16

__global__ __launch_bounds__(256) void gemm_kernel(const float* __restrict__ x,
                                                   const float* __restrict__ w,
                                                   float* __restrict__ xw) {
    __shared__ float lds_a[TK][TM];   // x tile, transposed: [k][row]
    __shared__ float lds_b[TK][TN];   // w tile: [k][col]

    const int tid = threadIdx.x;
    const int c0 = blockIdx.x * TN;   // 0 or 128
    const int r0 = blockIdx.y * TM;
    const int ty = tid >> 4;          // 0..15 -> row group (8 rows each)
    const int tx = tid & 15;          // 0..15 -> col group (8 cols each)

    float acc[8][8];
#pragma unroll
    for (int i = 0; i < 8; ++i)
#pragma unroll
        for (int j = 0; j < 8; ++j) acc[i][j] = 0.f;

    // A-load mapping: thread -> row tid>>1 (0..127), k-offset (tid&1)*8
    const int arow = tid >> 1;
    const int akk  = (tid & 1) * 8;
    const bool arow_ok = (r0 + arow) < N_NODES;
    // B-load mapping: thread -> k tid>>4 (0..15), col (tid&15)*8
    const int bkk = tid >> 4;
    const int bcc = (tid & 15) * 8;

    for (int k0 = 0; k0 < D_IN; k0 += TK) {
        // ---- stage A (transposed) ----
        float4 av0 = {0.f, 0.f, 0.f, 0.f}, av1 = {0.f, 0.f, 0.f, 0.f};
        if (arow_ok) {
            const float* src = x + (size_t)(r0 + arow) * D_IN + k0 + akk;
            av0 = *reinterpret_cast<const float4*>(src);
            av1 = *reinterpret_cast<const float4*>(src + 4);
        }
        lds_a[akk + 0][arow] = av0.x;
        lds_a[akk + 1][arow] = av0.y;
        lds_a[akk + 2][arow] = av0.z;
        lds_a[akk + 3][arow] = av0.w;
        lds_a[akk + 4][arow] = av1.x;
        lds_a[akk + 5][arow] = av1.y;
        lds_a[akk + 6][arow] = av1.z;
        lds_a[akk + 7][arow] = av1.w;
        // ---- stage B ----
        {
            const float* wsrc = w + (size_t)(k0 + bkk) * D_OUT + c0 + bcc;
            *reinterpret_cast<float4*>(&lds_b[bkk][bcc])     = *reinterpret_cast<const float4*>(wsrc);
            *reinterpret_cast<float4*>(&lds_b[bkk][bcc + 4]) = *reinterpret_cast<const float4*>(wsrc + 4);
        }
        __syncthreads();

#pragma unroll
        for (int kk = 0; kk < TK; ++kk) {
            float4 a0 = *reinterpret_cast<const float4*>(&lds_a[kk][ty * 8]);
            float4 a1 = *reinterpret_cast<const float4*>(&lds_a[kk][ty * 8 + 4]);
            float4 b0 = *reinterpret_cast<const float4*>(&lds_b[kk][tx * 8]);
            float4 b1 = *reinterpret_cast<const float4*>(&lds_b[kk][tx * 8 + 4]);
            float ar[8] = {a0.x, a0.y, a0.z, a0.w, a1.x, a1.y, a1.z, a1.w};
            float br[8] = {b0.x, b0.y, b0.z, b0.w, b1.x, b1.y, b1.z, b1.w};
#pragma unroll
            for (int i = 0; i < 8; ++i)
#pragma unroll
                for (int j = 0; j < 8; ++j)
                    acc[i][j] = fmaf(ar[i], br[j], acc[i][j]);
        }
        __syncthreads();
    }

#pragma unroll
    for (int i = 0; i < 8; ++i) {
        const int row = r0 + ty * 8 + i;
        if (row < N_NODES) {
            float4 s0 = {acc[i][0], acc[i][1], acc[i][2], acc[i][3]};
            float4 s1 = {acc[i][4], acc[i][5], acc[i][6], acc[i][7]};
            float* dst = xw + (size_t)row * D_OUT + c0 + tx * 8;
            *reinterpret_cast<float4*>(dst)     = s0;
            *reinterpret_cast<float4*>(dst + 4) = s1;
        }
    }
}

// ---------------------------------------------------------------------------
// CSR build
// ---------------------------------------------------------------------------
__global__ void zero_deg_kernel(int* __restrict__ deg) {
    int i = blockIdx.x * blockDim.x + threadIdx.x;
    if (i < N_NODES) deg[i] = 0;
}

__global__ void hist_kernel(const int* __restrict__ erow, int* __restrict__ deg) {
    for (int e = blockIdx.x * blockDim.x + threadIdx.x; e < N_EDGES;
         e += gridDim.x * blockDim.x) {
        atomicAdd(&deg[erow[e]], 1);
    }
}

#define SCAN_CHUNK 1024   // 256 threads x 4 elems

__global__ __launch_bounds__(256) void scan_part_kernel(const int* __restrict__ deg,
                                                        int* __restrict__ inc,
                                                        int* __restrict__ chunkSums) {
    __shared__ int lds[256];
    const int tid = threadIdx.x;
    const int base = blockIdx.x * SCAN_CHUNK;
    const int idx = base + tid * 4;
    int v0 = (idx + 0 < N_NODES) ? deg[idx + 0] : 0;
    int v1 = (idx + 1 < N_NODES) ? deg[idx + 1] : 0;
    int v2 = (idx + 2 < N_NODES) ? deg[idx + 2] : 0;
    int v3 = (idx + 3 < N_NODES) ? deg[idx + 3] : 0;
    v1 += v0; v2 += v1; v3 += v2;          // thread-local inclusive
    lds[tid] = v3;
    __syncthreads();
    for (int off = 1; off < 256; off <<= 1) {
        int t = (tid >= off) ? lds[tid - off] : 0;
        __syncthreads();
        lds[tid] += t;
        __syncthreads();
    }
    const int texc = (tid > 0) ? lds[tid - 1] : 0;
    if (idx + 0 < N_NODES) inc[idx + 0] = v0 + texc;
    if (idx + 1 < N_NODES) inc[idx + 1] = v1 + texc;
    if (idx + 2 < N_NODES) inc[idx + 2] = v2 + texc;
    if (idx + 3 < N_NODES) inc[idx + 3] = v3 + texc;
    if (tid == 255) chunkSums[blockIdx.x] = lds[255];
}

__global__ __launch_bounds__(128) void scan_chunks_kernel(const int* __restrict__ chunkSums,
                                                          int* __restrict__ chunkOffs,
                                                          int nChunks) {
    __shared__ int lds[128];
    const int tid = threadIdx.x;
    lds[tid] = (tid < nChunks) ? chunkSums[tid] : 0;
    __syncthreads();
    for (int off = 1; off < 128; off <<= 1) {
        int t = (tid >= off) ? lds[tid - off] : 0;
        __syncthreads();
        lds[tid] += t;
        __syncthreads();
    }
    if (tid < nChunks) chunkOffs[tid] = (tid > 0) ? lds[tid - 1] : 0;
}

__global__ void scan_final_kernel(const int* __restrict__ inc,
                                  const int* __restrict__ chunkOffs,
                                  int* __restrict__ rowptr,
                                  int* __restrict__ pos) {
    int i = blockIdx.x * blockDim.x + threadIdx.x;
    if (i < N_NODES) {
        int val = inc[i] + chunkOffs[i / SCAN_CHUNK];
        rowptr[i + 1] = val;
        if (i + 1 < N_NODES) pos[i + 1] = val;
        if (i == 0) { rowptr[0] = 0; pos[0] = 0; }
    }
}

__global__ void fill_csr_kernel(const int* __restrict__ erow,
                                const int* __restrict__ ecol,
                                const float* __restrict__ eval_,
                                int* __restrict__ pos,
                                int* __restrict__ ccol,
                                float* __restrict__ cval) {
    for (int e = blockIdx.x * blockDim.x + threadIdx.x; e < N_EDGES;
         e += gridDim.x * blockDim.x) {
        const int r = erow[e];
        const int p = atomicAdd(&pos[r], 1);
        ccol[p] = ecol[e];
        cval[p] = eval_[e];
    }
}

// ---------------------------------------------------------------------------
// Aggregate: one wave per node; lane = 4 consecutive f32 of the 256-wide row
// out[n] = relu(sum_e val_e * xw[col_e] + bias)
// ---------------------------------------------------------------------------
__global__ __launch_bounds__(256) void aggregate_kernel(const int* __restrict__ rowptr,
                                                        const int* __restrict__ ccol,
                                                        const float* __restrict__ cval,
                                                        const float* __restrict__ xw,
                                                        const float* __restrict__ bias,
                                                        float* __restrict__ out) {
    const int gid  = blockIdx.x * blockDim.x + threadIdx.x;
    const int nid  = gid >> 6;
    const int lane = gid & 63;
    if (nid >= N_NODES) return;

    const int beg = rowptr[nid];
    const int end = rowptr[nid + 1];
    const float4* __restrict__ xw4 = reinterpret_cast<const float4*>(xw);

    float4 acc = {0.f, 0.f, 0.f, 0.f};
    int e = beg;
    for (; e + 4 <= end; e += 4) {
        const int   c0 = ccol[e],     c1 = ccol[e + 1];
        const int   c2 = ccol[e + 2], c3 = ccol[e + 3];
        const float v0 = cval[e],     v1 = cval[e + 1];
        const float v2 = cval[e + 2], v3 = cval[e + 3];
        const float4 m0 = xw4[(size_t)c0 * 64 + lane];
        const float4 m1 = xw4[(size_t)c1 * 64 + lane];
        const float4 m2 = xw4[(size_t)c2 * 64 + lane];
        const float4 m3 = xw4[(size_t)c3 * 64 + lane];
        acc.x = fmaf(v0, m0.x, acc.x); acc.y = fmaf(v0, m0.y, acc.y);
        acc.z = fmaf(v0, m0.z, acc.z); acc.w = fmaf(v0, m0.w, acc.w);
        acc.x = fmaf(v1, m1.x, acc.x); acc.y = fmaf(v1, m1.y, acc.y);
        acc.z = fmaf(v1, m1.z, acc.z); acc.w = fmaf(v1, m1.w, acc.w);
        acc.x = fmaf(v2, m2.x, acc.x); acc.y = fmaf(v2, m2.y, acc.y);
        acc.z = fmaf(v2, m2.z, acc.z); acc.w = fmaf(v2, m2.w, acc.w);
        acc.x = fmaf(v3, m3.x, acc.x); acc.y = fmaf(v3, m3.y, acc.y);
        acc.z = fmaf(v3, m3.z, acc.z); acc.w = fmaf(v3, m3.w, acc.w);
    }
    for (; e < end; ++e) {
        const int   c = ccol[e];
        const float v = cval[e];
        const float4 m = xw4[(size_t)c * 64 + lane];
        acc.x = fmaf(v, m.x, acc.x); acc.y = fmaf(v, m.y, acc.y);
        acc.z = fmaf(v, m.z, acc.z); acc.w = fmaf(v, m.w, acc.w);
    }

    const float4 b = reinterpret_cast<const float4*>(bias)[lane];
    float4 r;
    r.x = fmaxf(acc.x + b.x, 0.f);
    r.y = fmaxf(acc.y + b.y, 0.f);
    r.z = fmaxf(acc.z + b.z, 0.f);
    r.w = fmaxf(acc.w + b.w, 0.f);
    reinterpret_cast<float4*>(out)[(size_t)nid * 64 + lane] = r;
}

// ---------------------------------------------------------------------------
extern "C" void kernel_launch(void* const* d_in, const int* in_sizes, int n_in,
                              void* d_out, int out_size, void* d_ws, size_t ws_size,
                              hipStream_t stream) {
    const float* x     = (const float*)d_in[0];
    const int*   erow  = (const int*)d_in[1];
    const int*   ecol  = (const int*)d_in[2];
    const float* eval_ = (const float*)d_in[3];
    const float* w     = (const float*)d_in[4];
    const float* bias  = (const float*)d_in[5];
    float* out = (float*)d_out;

    char* ws = (char*)d_ws;
    size_t o = 0;
    float* xw      = (float*)(ws + o); o += (size_t)N_NODES * D_OUT * 4;          // 102.4 MB
    int*   rowptr  = (int*)(ws + o);   o += (((size_t)(N_NODES + 1) * 4) + 15) & ~(size_t)15;
    int*   pos     = (int*)(ws + o);   o += (size_t)N_NODES * 4;
    int*   deg     = (int*)(ws + o);   o += (size_t)N_NODES * 4;
    int*   inc     = (int*)(ws + o);   o += (size_t)N_NODES * 4;
    int*   chunkS  = (int*)(ws + o);   o += 1024;
    int*   chunkO  = (int*)(ws + o);   o += 1024;
    int*   ccol    = (int*)(ws + o);   o += (size_t)N_EDGES * 4;
    float* cval    = (float*)(ws + o); o += (size_t)N_EDGES * 4;

    const int nChunks = (N_NODES + SCAN_CHUNK - 1) / SCAN_CHUNK;   // 98

    // GEMM: xw = x @ W
    dim3 ggrid(D_OUT / TN, (N_NODES + TM - 1) / TM);
    gemm_kernel<<<ggrid, 256, 0, stream>>>(x, w, xw);

    // CSR build
    zero_deg_kernel<<<(N_NODES + 255) / 256, 256, 0, stream>>>(deg);
    hist_kernel<<<2048, 256, 0, stream>>>(erow, deg);
    scan_part_kernel<<<nChunks, 256, 0, stream>>>(deg, inc, chunkS);
    scan_chunks_kernel<<<1, 128, 0, stream>>>(chunkS, chunkO, nChunks);
    scan_final_kernel<<<(N_NODES + 255) / 256, 256, 0, stream>>>(inc, chunkO, rowptr, pos);
    fill_csr_kernel<<<2048, 256, 0, stream>>>(erow, ecol, eval_, pos, ccol, cval);

    // Aggregate + bias + relu
    aggregate_kernel<<<(N_NODES * 64) / 256, 256, 0, stream>>>(rowptr, ccol, cval, xw, bias, out);
}

// Round 2
// 1206.781 us; speedup vs baseline: 1.1314x; 1.1314x over previous
//
#include <hip/hip_runtime.h>

#define N_NODES 100000
#define N_EDGES 3200000
#define D_IN    512
#define D_OUT   256

typedef short sh8 __attribute__((ext_vector_type(8)));
typedef float f4  __attribute__((ext_vector_type(4)));

__device__ __forceinline__ unsigned short bf16rn(float f) {
    unsigned u = __float_as_uint(f);
    unsigned r = (u + 0x7FFFu + ((u >> 16) & 1u)) >> 16;
    return (unsigned short)r;
}

__device__ __forceinline__ void gload_lds16(const void* g, void* l) {
    __builtin_amdgcn_global_load_lds(
        (const __attribute__((address_space(1))) void*)g,
        (__attribute__((address_space(3))) void*)l, 16, 0, 0);
}

// ---------------------------------------------------------------------------
// Pack W[512][256] fp32 -> bf16 hi/lo in MFMA-fragment-major order:
// wp elems: (((s*16 + b)*2 + h)*64 + lane)*8 + j
//   where n = b*16 + (lane&15), k = s*32 + (lane>>4)*8 + j
// ---------------------------------------------------------------------------
__global__ __launch_bounds__(256) void wpack_kernel(const float* __restrict__ w,
                                                    short* __restrict__ wp) {
    const int id = blockIdx.x * 256 + threadIdx.x;   // 0..16383
    const int l = id & 63;
    const int b = (id >> 6) & 15;
    const int s = id >> 10;
    const int n  = b * 16 + (l & 15);
    const int k0 = s * 32 + (l >> 4) * 8;
    sh8 hi8, lo8;
#pragma unroll
    for (int j = 0; j < 8; ++j) {
        float f = w[(size_t)(k0 + j) * D_OUT + n];
        unsigned short h = bf16rn(f);
        float fh = __uint_as_float((unsigned)h << 16);
        hi8[j] = (short)h;
        lo8[j] = (short)bf16rn(f - fh);
    }
    short* dst = wp + (size_t)(s * 16 + b) * 1024 + (size_t)l * 8;
    *reinterpret_cast<sh8*>(dst)       = hi8;
    *reinterpret_cast<sh8*>(dst + 512) = lo8;
}

// ---------------------------------------------------------------------------
// GEMM: xw[N,256] = x[N,512] @ W — split-bf16 MFMA (hi*hi + hi*lo + lo*hi)
// Block: 256 thr (4 waves), BM=64, BN=256 (wave w -> cols w*64..+63), BK=32
// ---------------------------------------------------------------------------
__global__ __launch_bounds__(256) void gemm_mfma(const float* __restrict__ x,
                                                 const short* __restrict__ wp,
                                                 float* __restrict__ xw) {
    __shared__ __align__(16) short A_lds[64 * 64];    // 8 KB: row*128B, 8 granules XOR-swizzled (hi g0-3, lo g4-7)
    __shared__ __align__(16) short B_lds[16384];      // 32 KB: [nblk][hilo][lane][8] linear

    const int tid  = threadIdx.x;
    const int wave = tid >> 6;
    const int lane = tid & 63;
    const int r0   = blockIdx.x * 64;

    f4 acc[4][4];
#pragma unroll
    for (int i = 0; i < 4; ++i)
#pragma unroll
        for (int j = 0; j < 4; ++j) acc[i][j] = (f4){0.f, 0.f, 0.f, 0.f};

    // A staging mapping: thread t -> row sr=t>>2, k-granule skg=t&3 (8 floats)
    const int sr  = tid >> 2;
    const int skg = tid & 3;
    const int grow = r0 + sr;
    const bool rok = grow < N_NODES;
    const float* xbase = x + (size_t)grow * D_IN + skg * 8;
    const int aw_hi = sr * 128 + ((skg ^ (sr & 7)) << 4);
    const int aw_lo = aw_hi ^ 0x40;
    char* Ac = reinterpret_cast<char*>(A_lds);
    char* Bc = reinterpret_cast<char*>(B_lds);

    // frag-read constants
    const int kg  = lane >> 4;
    const int l7  = lane & 7;
    const int l15 = lane & 15;

    for (int s = 0; s < 16; ++s) {
        // ---- stage B (async, linear LDS) ----
        const short* bs = wp + (size_t)s * 16384;
#pragma unroll
        for (int rr = 0; rr < 8; ++rr) {
            gload_lds16(bs + rr * 2048 + tid * 8, &B_lds[rr * 2048 + wave * 512]);
        }
        // ---- stage A: load fp32, split to bf16 hi/lo, swizzled ds_write ----
        float fv[8] = {0.f, 0.f, 0.f, 0.f, 0.f, 0.f, 0.f, 0.f};
        if (rok) {
            float4 v0 = *reinterpret_cast<const float4*>(xbase + s * 32);
            float4 v1 = *reinterpret_cast<const float4*>(xbase + s * 32 + 4);
            fv[0] = v0.x; fv[1] = v0.y; fv[2] = v0.z; fv[3] = v0.w;
            fv[4] = v1.x; fv[5] = v1.y; fv[6] = v1.z; fv[7] = v1.w;
        }
        sh8 hi8, lo8;
#pragma unroll
        for (int j = 0; j < 8; ++j) {
            unsigned short h = bf16rn(fv[j]);
            float fh = __uint_as_float((unsigned)h << 16);
            hi8[j] = (short)h;
            lo8[j] = (short)bf16rn(fv[j] - fh);
        }
        *reinterpret_cast<sh8*>(Ac + aw_hi) = hi8;
        *reinterpret_cast<sh8*>(Ac + aw_lo) = lo8;
        __syncthreads();

        // ---- fragments ----
        sh8 ah[4], al[4], bh[4], bl[4];
#pragma unroll
        for (int mf = 0; mf < 4; ++mf) {
            const int rowb = (mf * 16 + l15) * 128;
            const int ghi  = (kg ^ l7) << 4;
            ah[mf] = *reinterpret_cast<const sh8*>(Ac + rowb + ghi);
            al[mf] = *reinterpret_cast<const sh8*>(Ac + rowb + (ghi ^ 0x40));
        }
#pragma unroll
        for (int nf = 0; nf < 4; ++nf) {
            const int base = (wave * 4 + nf) * 2048 + lane * 16;
            bh[nf] = *reinterpret_cast<const sh8*>(Bc + base);
            bl[nf] = *reinterpret_cast<const sh8*>(Bc + base + 1024);
        }
        // ---- MFMA: 48 per K-step ----
#pragma unroll
        for (int mf = 0; mf < 4; ++mf)
#pragma unroll
            for (int nf = 0; nf < 4; ++nf) {
                acc[mf][nf] = __builtin_amdgcn_mfma_f32_16x16x32_bf16(ah[mf], bh[nf], acc[mf][nf], 0, 0, 0);
                acc[mf][nf] = __builtin_amdgcn_mfma_f32_16x16x32_bf16(ah[mf], bl[nf], acc[mf][nf], 0, 0, 0);
                acc[mf][nf] = __builtin_amdgcn_mfma_f32_16x16x32_bf16(al[mf], bh[nf], acc[mf][nf], 0, 0, 0);
            }
        __syncthreads();
    }

    // ---- epilogue: C/D col=lane&15, row=(lane>>4)*4+reg ----
    const int orow = (lane >> 4) * 4;
    const int ocol = wave * 64 + l15;
#pragma unroll
    for (int mf = 0; mf < 4; ++mf) {
#pragma unroll
        for (int rg = 0; rg < 4; ++rg) {
            const int row = r0 + mf * 16 + orow + rg;
            if (row < N_NODES) {
                float* dst = xw + (size_t)row * D_OUT + ocol;
#pragma unroll
                for (int nf = 0; nf < 4; ++nf) dst[nf * 16] = acc[mf][nf][rg];
            }
        }
    }
}

// ---------------------------------------------------------------------------
// CSR build
// ---------------------------------------------------------------------------
__global__ void zero_deg_kernel(int* __restrict__ deg) {
    int i = blockIdx.x * blockDim.x + threadIdx.x;
    if (i < N_NODES) deg[i] = 0;
}

__global__ void hist_kernel(const int* __restrict__ erow, int* __restrict__ deg) {
    for (int e = blockIdx.x * blockDim.x + threadIdx.x; e < N_EDGES;
         e += gridDim.x * blockDim.x) {
        atomicAdd(&deg[erow[e]], 1);
    }
}

#define SCAN_CHUNK 1024

__global__ __launch_bounds__(256) void scan_part_kernel(const int* __restrict__ deg,
                                                        int* __restrict__ inc,
                                                        int* __restrict__ chunkSums) {
    __shared__ int lds[256];
    const int tid = threadIdx.x;
    const int idx = blockIdx.x * SCAN_CHUNK + tid * 4;
    int v0 = (idx + 0 < N_NODES) ? deg[idx + 0] : 0;
    int v1 = (idx + 1 < N_NODES) ? deg[idx + 1] : 0;
    int v2 = (idx + 2 < N_NODES) ? deg[idx + 2] : 0;
    int v3 = (idx + 3 < N_NODES) ? deg[idx + 3] : 0;
    v1 += v0; v2 += v1; v3 += v2;
    lds[tid] = v3;
    __syncthreads();
    for (int off = 1; off < 256; off <<= 1) {
        int t = (tid >= off) ? lds[tid - off] : 0;
        __syncthreads();
        lds[tid] += t;
        __syncthreads();
    }
    const int texc = (tid > 0) ? lds[tid - 1] : 0;
    if (idx + 0 < N_NODES) inc[idx + 0] = v0 + texc;
    if (idx + 1 < N_NODES) inc[idx + 1] = v1 + texc;
    if (idx + 2 < N_NODES) inc[idx + 2] = v2 + texc;
    if (idx + 3 < N_NODES) inc[idx + 3] = v3 + texc;
    if (tid == 255) chunkSums[blockIdx.x] = lds[255];
}

__global__ __launch_bounds__(128) void scan_chunks_kernel(const int* __restrict__ chunkSums,
                                                          int* __restrict__ chunkOffs,
                                                          int nChunks) {
    __shared__ int lds[128];
    const int tid = threadIdx.x;
    lds[tid] = (tid < nChunks) ? chunkSums[tid] : 0;
    __syncthreads();
    for (int off = 1; off < 128; off <<= 1) {
        int t = (tid >= off) ? lds[tid - off] : 0;
        __syncthreads();
        lds[tid] += t;
        __syncthreads();
    }
    if (tid < nChunks) chunkOffs[tid] = (tid > 0) ? lds[tid - 1] : 0;
}

__global__ void scan_final_kernel(const int* __restrict__ inc,
                                  const int* __restrict__ chunkOffs,
                                  int* __restrict__ rowptr,
                                  int* __restrict__ pos) {
    int i = blockIdx.x * blockDim.x + threadIdx.x;
    if (i < N_NODES) {
        int val = inc[i] + chunkOffs[i / SCAN_CHUNK];
        rowptr[i + 1] = val;
        if (i + 1 < N_NODES) pos[i + 1] = val;
        if (i == 0) { rowptr[0] = 0; pos[0] = 0; }
    }
}

__global__ void fill_csr_kernel(const int* __restrict__ erow,
                                const int* __restrict__ ecol,
                                const float* __restrict__ eval_,
                                int* __restrict__ pos,
                                int2* __restrict__ cpack) {
    for (int e = blockIdx.x * blockDim.x + threadIdx.x; e < N_EDGES;
         e += gridDim.x * blockDim.x) {
        const int r = erow[e];
        const int p = atomicAdd(&pos[r], 1);
        int2 pk;
        pk.x = ecol[e];
        pk.y = __float_as_int(eval_[e]);
        cpack[p] = pk;
    }
}

// ---------------------------------------------------------------------------
// Aggregate: one wave per node; lane = 4 consecutive f32 of the 256-wide row
// ---------------------------------------------------------------------------
__global__ __launch_bounds__(256) void aggregate_kernel(const int* __restrict__ rowptr,
                                                        const int2* __restrict__ cpack,
                                                        const float* __restrict__ xw,
                                                        const float* __restrict__ bias,
                                                        float* __restrict__ out) {
    const int gid  = blockIdx.x * blockDim.x + threadIdx.x;
    const int nid  = gid >> 6;
    const int lane = gid & 63;
    if (nid >= N_NODES) return;

    const int beg = rowptr[nid];
    const int end = rowptr[nid + 1];
    const float4* __restrict__ xw4 = reinterpret_cast<const float4*>(xw);

    float4 acc = {0.f, 0.f, 0.f, 0.f};
    int e = beg;
    for (; e + 4 <= end; e += 4) {
        const int2 p0 = cpack[e],     p1 = cpack[e + 1];
        const int2 p2 = cpack[e + 2], p3 = cpack[e + 3];
        const float4 m0 = xw4[(size_t)p0.x * 64 + lane];
        const float4 m1 = xw4[(size_t)p1.x * 64 + lane];
        const float4 m2 = xw4[(size_t)p2.x * 64 + lane];
        const float4 m3 = xw4[(size_t)p3.x * 64 + lane];
        const float v0 = __int_as_float(p0.y), v1 = __int_as_float(p1.y);
        const float v2 = __int_as_float(p2.y), v3 = __int_as_float(p3.y);
        acc.x = fmaf(v0, m0.x, acc.x); acc.y = fmaf(v0, m0.y, acc.y);
        acc.z = fmaf(v0, m0.z, acc.z); acc.w = fmaf(v0, m0.w, acc.w);
        acc.x = fmaf(v1, m1.x, acc.x); acc.y = fmaf(v1, m1.y, acc.y);
        acc.z = fmaf(v1, m1.z, acc.z); acc.w = fmaf(v1, m1.w, acc.w);
        acc.x = fmaf(v2, m2.x, acc.x); acc.y = fmaf(v2, m2.y, acc.y);
        acc.z = fmaf(v2, m2.z, acc.z); acc.w = fmaf(v2, m2.w, acc.w);
        acc.x = fmaf(v3, m3.x, acc.x); acc.y = fmaf(v3, m3.y, acc.y);
        acc.z = fmaf(v3, m3.z, acc.z); acc.w = fmaf(v3, m3.w, acc.w);
    }
    for (; e < end; ++e) {
        const int2 p = cpack[e];
        const float v = __int_as_float(p.y);
        const float4 m = xw4[(size_t)p.x * 64 + lane];
        acc.x = fmaf(v, m.x, acc.x); acc.y = fmaf(v, m.y, acc.y);
        acc.z = fmaf(v, m.z, acc.z); acc.w = fmaf(v, m.w, acc.w);
    }

    const float4 b = reinterpret_cast<const float4*>(bias)[lane];
    float4 r;
    r.x = fmaxf(acc.x + b.x, 0.f);
    r.y = fmaxf(acc.y + b.y, 0.f);
    r.z = fmaxf(acc.z + b.z, 0.f);
    r.w = fmaxf(acc.w + b.w, 0.f);
    reinterpret_cast<float4*>(out)[(size_t)nid * 64 + lane] = r;
}

// ---------------------------------------------------------------------------
extern "C" void kernel_launch(void* const* d_in, const int* in_sizes, int n_in,
                              void* d_out, int out_size, void* d_ws, size_t ws_size,
                              hipStream_t stream) {
    const float* x     = (const float*)d_in[0];
    const int*   erow  = (const int*)d_in[1];
    const int*   ecol  = (const int*)d_in[2];
    const float* eval_ = (const float*)d_in[3];
    const float* w     = (const float*)d_in[4];
    const float* bias  = (const float*)d_in[5];
    float* out = (float*)d_out;

    char* ws = (char*)d_ws;
    size_t o = 0;
    float* xw      = (float*)(ws + o); o += (size_t)N_NODES * D_OUT * 4;          // 102.4 MB
    short* wp      = (short*)(ws + o); o += (size_t)16 * 16384 * 2;               // 512 KB packed W
    int*   rowptr  = (int*)(ws + o);   o += (((size_t)(N_NODES + 1) * 4) + 15) & ~(size_t)15;
    int*   pos     = (int*)(ws + o);   o += (size_t)N_NODES * 4;
    int*   deg     = (int*)(ws + o);   o += (size_t)N_NODES * 4;
    int*   inc     = (int*)(ws + o);   o += (size_t)N_NODES * 4;
    int*   chunkS  = (int*)(ws + o);   o += 1024;
    int*   chunkO  = (int*)(ws + o);   o += 1024;
    int2*  cpack   = (int2*)(ws + o);  o += (size_t)N_EDGES * 8;                  // 25.6 MB

    const int nChunks = (N_NODES + SCAN_CHUNK - 1) / SCAN_CHUNK;   // 98

    // W pack + GEMM
    wpack_kernel<<<64, 256, 0, stream>>>(w, wp);
    gemm_mfma<<<(N_NODES + 63) / 64, 256, 0, stream>>>(x, wp, xw);

    // CSR build
    zero_deg_kernel<<<(N_NODES + 255) / 256, 256, 0, stream>>>(deg);
    hist_kernel<<<2048, 256, 0, stream>>>(erow, deg);
    scan_part_kernel<<<nChunks, 256, 0, stream>>>(deg, inc, chunkS);
    scan_chunks_kernel<<<1, 128, 0, stream>>>(chunkS, chunkO, nChunks);
    scan_final_kernel<<<(N_NODES + 255) / 256, 256, 0, stream>>>(inc, chunkO, rowptr, pos);
    fill_csr_kernel<<<2048, 256, 0, stream>>>(erow, ecol, eval_, pos, cpack);

    // Aggregate + bias + relu
    aggregate_kernel<<<(N_NODES * 64) / 256, 256, 0, stream>>>(rowptr, cpack, xw, bias, out);
}

// Round 5
// 968.755 us; speedup vs baseline: 1.4094x; 1.2457x over previous
//
#include <hip/hip_runtime.h>

#define N_NODES 100000
#define N_EDGES 3200000
#define D_IN    512
#define D_OUT   256

typedef short sh8 __attribute__((ext_vector_type(8)));
typedef float f4  __attribute__((ext_vector_type(4)));

__device__ __forceinline__ unsigned short bf16rn(float f) {
    unsigned u = __float_as_uint(f);
    unsigned r = (u + 0x7FFFu + ((u >> 16) & 1u)) >> 16;
    return (unsigned short)r;
}

__device__ __forceinline__ float bf2f(unsigned short h) {
    return __uint_as_float((unsigned)h << 16);
}

__device__ __forceinline__ void gload_lds16(const void* g, void* l) {
    __builtin_amdgcn_global_load_lds(
        (const __attribute__((address_space(1))) void*)g,
        (__attribute__((address_space(3))) void*)l, 16, 0, 0);
}

// ---------------------------------------------------------------------------
// Pack W[512][256] fp32 -> bf16 hi/lo in MFMA-fragment-major order:
// wp elems: (((s*16 + b)*2 + h)*64 + lane)*8 + j
//   where n = b*16 + (lane&15), k = s*32 + (lane>>4)*8 + j
// ---------------------------------------------------------------------------
__global__ __launch_bounds__(256) void wpack_kernel(const float* __restrict__ w,
                                                    short* __restrict__ wp) {
    const int id = blockIdx.x * 256 + threadIdx.x;   // 0..16383
    const int l = id & 63;
    const int b = (id >> 6) & 15;
    const int s = id >> 10;
    const int n  = b * 16 + (l & 15);
    const int k0 = s * 32 + (l >> 4) * 8;
    sh8 hi8, lo8;
#pragma unroll
    for (int j = 0; j < 8; ++j) {
        float f = w[(size_t)(k0 + j) * D_OUT + n];
        unsigned short h = bf16rn(f);
        float fh = bf2f(h);
        hi8[j] = (short)h;
        lo8[j] = (short)bf16rn(f - fh);
    }
    short* dst = wp + (size_t)(s * 16 + b) * 1024 + (size_t)l * 8;
    *reinterpret_cast<sh8*>(dst)       = hi8;
    *reinterpret_cast<sh8*>(dst + 512) = lo8;
}

// ---------------------------------------------------------------------------
// GEMM: xw_bf16[N,256] = x[N,512] @ W — split-bf16 MFMA (hi*hi + hi*lo + lo*hi)
// Block: 256 thr (4 waves), BM=64, BN=256 (wave w -> cols w*64..+63), BK=32
// ---------------------------------------------------------------------------
__global__ __launch_bounds__(256) void gemm_mfma(const float* __restrict__ x,
                                                 const short* __restrict__ wp,
                                                 unsigned short* __restrict__ xwh) {
    __shared__ __align__(16) short A_lds[64 * 64];    // 8 KB: row*128B, 8 granules XOR-swizzled (hi g0-3, lo g4-7)
    __shared__ __align__(16) short B_lds[16384];      // 32 KB: [nblk][hilo][lane][8] linear

    const int tid  = threadIdx.x;
    const int wave = tid >> 6;
    const int lane = tid & 63;
    const int r0   = blockIdx.x * 64;

    f4 acc[4][4];
#pragma unroll
    for (int i = 0; i < 4; ++i)
#pragma unroll
        for (int j = 0; j < 4; ++j) acc[i][j] = (f4){0.f, 0.f, 0.f, 0.f};

    // A staging mapping: thread t -> row sr=t>>2, k-granule skg=t&3 (8 floats)
    const int sr  = tid >> 2;
    const int skg = tid & 3;
    const int grow = r0 + sr;
    const bool rok = grow < N_NODES;
    const float* xbase = x + (size_t)grow * D_IN + skg * 8;
    const int aw_hi = sr * 128 + ((skg ^ (sr & 7)) << 4);
    const int aw_lo = aw_hi ^ 0x40;
    char* Ac = reinterpret_cast<char*>(A_lds);
    char* Bc = reinterpret_cast<char*>(B_lds);

    // frag-read constants
    const int kg  = lane >> 4;
    const int l7  = lane & 7;
    const int l15 = lane & 15;

    for (int s = 0; s < 16; ++s) {
        // ---- stage B (async, linear LDS) ----
        const short* bs = wp + (size_t)s * 16384;
#pragma unroll
        for (int rr = 0; rr < 8; ++rr) {
            gload_lds16(bs + rr * 2048 + tid * 8, &B_lds[rr * 2048 + wave * 512]);
        }
        // ---- stage A: load fp32, split to bf16 hi/lo, swizzled ds_write ----
        float fv[8] = {0.f, 0.f, 0.f, 0.f, 0.f, 0.f, 0.f, 0.f};
        if (rok) {
            float4 v0 = *reinterpret_cast<const float4*>(xbase + s * 32);
            float4 v1 = *reinterpret_cast<const float4*>(xbase + s * 32 + 4);
            fv[0] = v0.x; fv[1] = v0.y; fv[2] = v0.z; fv[3] = v0.w;
            fv[4] = v1.x; fv[5] = v1.y; fv[6] = v1.z; fv[7] = v1.w;
        }
        sh8 hi8, lo8;
#pragma unroll
        for (int j = 0; j < 8; ++j) {
            unsigned short h = bf16rn(fv[j]);
            float fh = bf2f(h);
            hi8[j] = (short)h;
            lo8[j] = (short)bf16rn(fv[j] - fh);
        }
        *reinterpret_cast<sh8*>(Ac + aw_hi) = hi8;
        *reinterpret_cast<sh8*>(Ac + aw_lo) = lo8;
        __syncthreads();

        // ---- fragments ----
        sh8 ah[4], al[4], bh[4], bl[4];
#pragma unroll
        for (int mf = 0; mf < 4; ++mf) {
            const int rowb = (mf * 16 + l15) * 128;
            const int ghi  = (kg ^ l7) << 4;
            ah[mf] = *reinterpret_cast<const sh8*>(Ac + rowb + ghi);
            al[mf] = *reinterpret_cast<const sh8*>(Ac + rowb + (ghi ^ 0x40));
        }
#pragma unroll
        for (int nf = 0; nf < 4; ++nf) {
            const int base = (wave * 4 + nf) * 2048 + lane * 16;
            bh[nf] = *reinterpret_cast<const sh8*>(Bc + base);
            bl[nf] = *reinterpret_cast<const sh8*>(Bc + base + 1024);
        }
        // ---- MFMA: 48 per K-step ----
#pragma unroll
        for (int mf = 0; mf < 4; ++mf)
#pragma unroll
            for (int nf = 0; nf < 4; ++nf) {
                acc[mf][nf] = __builtin_amdgcn_mfma_f32_16x16x32_bf16(ah[mf], bh[nf], acc[mf][nf], 0, 0, 0);
                acc[mf][nf] = __builtin_amdgcn_mfma_f32_16x16x32_bf16(ah[mf], bl[nf], acc[mf][nf], 0, 0, 0);
                acc[mf][nf] = __builtin_amdgcn_mfma_f32_16x16x32_bf16(al[mf], bh[nf], acc[mf][nf], 0, 0, 0);
            }
        __syncthreads();
    }

    // ---- epilogue: C/D col=lane&15, row=(lane>>4)*4+reg; write bf16 ----
    const int orow = (lane >> 4) * 4;
    const int ocol = wave * 64 + l15;
#pragma unroll
    for (int mf = 0; mf < 4; ++mf) {
#pragma unroll
        for (int rg = 0; rg < 4; ++rg) {
            const int row = r0 + mf * 16 + orow + rg;
            if (row < N_NODES) {
                unsigned short* dst = xwh + (size_t)row * D_OUT + ocol;
#pragma unroll
                for (int nf = 0; nf < 4; ++nf) dst[nf * 16] = bf16rn(acc[mf][nf][rg]);
            }
        }
    }
}

// ---------------------------------------------------------------------------
// CSR build
// ---------------------------------------------------------------------------
__global__ void zero_deg_kernel(int* __restrict__ deg) {
    int i = blockIdx.x * blockDim.x + threadIdx.x;
    if (i < N_NODES) deg[i] = 0;
}

__global__ void hist_kernel(const int* __restrict__ erow, int* __restrict__ deg) {
    for (int e = blockIdx.x * blockDim.x + threadIdx.x; e < N_EDGES;
         e += gridDim.x * blockDim.x) {
        atomicAdd(&deg[erow[e]], 1);
    }
}

#define SCAN_CHUNK 1024

__global__ __launch_bounds__(256) void scan_part_kernel(const int* __restrict__ deg,
                                                        int* __restrict__ inc,
                                                        int* __restrict__ chunkSums) {
    __shared__ int lds[256];
    const int tid = threadIdx.x;
    const int idx = blockIdx.x * SCAN_CHUNK + tid * 4;
    int v0 = (idx + 0 < N_NODES) ? deg[idx + 0] : 0;
    int v1 = (idx + 1 < N_NODES) ? deg[idx + 1] : 0;
    int v2 = (idx + 2 < N_NODES) ? deg[idx + 2] : 0;
    int v3 = (idx + 3 < N_NODES) ? deg[idx + 3] : 0;
    v1 += v0; v2 += v1; v3 += v2;
    lds[tid] = v3;
    __syncthreads();
    for (int off = 1; off < 256; off <<= 1) {
        int t = (tid >= off) ? lds[tid - off] : 0;
        __syncthreads();
        lds[tid] += t;
        __syncthreads();
    }
    const int texc = (tid > 0) ? lds[tid - 1] : 0;
    if (idx + 0 < N_NODES) inc[idx + 0] = v0 + texc;
    if (idx + 1 < N_NODES) inc[idx + 1] = v1 + texc;
    if (idx + 2 < N_NODES) inc[idx + 2] = v2 + texc;
    if (idx + 3 < N_NODES) inc[idx + 3] = v3 + texc;
    if (tid == 255) chunkSums[blockIdx.x] = lds[255];
}

__global__ __launch_bounds__(128) void scan_chunks_kernel(const int* __restrict__ chunkSums,
                                                          int* __restrict__ chunkOffs,
                                                          int nChunks) {
    __shared__ int lds[128];
    const int tid = threadIdx.x;
    lds[tid] = (tid < nChunks) ? chunkSums[tid] : 0;
    __syncthreads();
    for (int off = 1; off < 128; off <<= 1) {
        int t = (tid >= off) ? lds[tid - off] : 0;
        __syncthreads();
        lds[tid] += t;
        __syncthreads();
    }
    if (tid < nChunks) chunkOffs[tid] = (tid > 0) ? lds[tid - 1] : 0;
}

__global__ void scan_final_kernel(const int* __restrict__ inc,
                                  const int* __restrict__ chunkOffs,
                                  int* __restrict__ rowptr,
                                  int* __restrict__ pos) {
    int i = blockIdx.x * blockDim.x + threadIdx.x;
    if (i < N_NODES) {
        int val = inc[i] + chunkOffs[i / SCAN_CHUNK];
        rowptr[i + 1] = val;
        if (i + 1 < N_NODES) pos[i + 1] = val;
        if (i == 0) { rowptr[0] = 0; pos[0] = 0; }
    }
}

__global__ void fill_csr_kernel(const int* __restrict__ erow,
                                const int* __restrict__ ecol,
                                const float* __restrict__ eval_,
                                int* __restrict__ pos,
                                int2* __restrict__ cpack) {
    for (int e = blockIdx.x * blockDim.x + threadIdx.x; e < N_EDGES;
         e += gridDim.x * blockDim.x) {
        const int r = erow[e];
        const int p = atomicAdd(&pos[r], 1);
        int2 pk;
        pk.x = ecol[e];
        pk.y = __float_as_int(eval_[e]);
        cpack[p] = pk;
    }
}

// ---------------------------------------------------------------------------
// Aggregate: one wave per node; lane = 4 consecutive bf16 cols (8B gather)
// out[n] = relu(sum_e val_e * xw_bf16[col_e] + bias)   (fp32 accumulate)
// ---------------------------------------------------------------------------
__global__ __launch_bounds__(256) void aggregate_kernel(const int* __restrict__ rowptr,
                                                        const int2* __restrict__ cpack,
                                                        const ushort4* __restrict__ xwh4,
                                                        const float* __restrict__ bias,
                                                        float* __restrict__ out) {
    const int gid  = blockIdx.x * blockDim.x + threadIdx.x;
    const int nid  = gid >> 6;
    const int lane = gid & 63;
    if (nid >= N_NODES) return;

    const int beg = rowptr[nid];
    const int end = rowptr[nid + 1];

    float4 acc = {0.f, 0.f, 0.f, 0.f};
    int e = beg;
    for (; e + 8 <= end; e += 8) {
        int2 p[8];
        ushort4 m[8];
#pragma unroll
        for (int j = 0; j < 8; ++j) p[j] = cpack[e + j];
#pragma unroll
        for (int j = 0; j < 8; ++j) m[j] = xwh4[(size_t)p[j].x * 64 + lane];
#pragma unroll
        for (int j = 0; j < 8; ++j) {
            const float v = __int_as_float(p[j].y);
            acc.x = fmaf(v, bf2f(m[j].x), acc.x);
            acc.y = fmaf(v, bf2f(m[j].y), acc.y);
            acc.z = fmaf(v, bf2f(m[j].z), acc.z);
            acc.w = fmaf(v, bf2f(m[j].w), acc.w);
        }
    }
    for (; e < end; ++e) {
        const int2 p = cpack[e];
        const float v = __int_as_float(p.y);
        const ushort4 m = xwh4[(size_t)p.x * 64 + lane];
        acc.x = fmaf(v, bf2f(m.x), acc.x);
        acc.y = fmaf(v, bf2f(m.y), acc.y);
        acc.z = fmaf(v, bf2f(m.z), acc.z);
        acc.w = fmaf(v, bf2f(m.w), acc.w);
    }

    const float4 b = reinterpret_cast<const float4*>(bias)[lane];
    float4 r;
    r.x = fmaxf(acc.x + b.x, 0.f);
    r.y = fmaxf(acc.y + b.y, 0.f);
    r.z = fmaxf(acc.z + b.z, 0.f);
    r.w = fmaxf(acc.w + b.w, 0.f);
    reinterpret_cast<float4*>(out)[(size_t)nid * 64 + lane] = r;
}

// ---------------------------------------------------------------------------
extern "C" void kernel_launch(void* const* d_in, const int* in_sizes, int n_in,
                              void* d_out, int out_size, void* d_ws, size_t ws_size,
                              hipStream_t stream) {
    const float* x     = (const float*)d_in[0];
    const int*   erow  = (const int*)d_in[1];
    const int*   ecol  = (const int*)d_in[2];
    const float* eval_ = (const float*)d_in[3];
    const float* w     = (const float*)d_in[4];
    const float* bias  = (const float*)d_in[5];
    float* out = (float*)d_out;

    char* ws = (char*)d_ws;
    size_t o = 0;
    unsigned short* xwh = (unsigned short*)(ws + o); o += (size_t)N_NODES * D_OUT * 2;  // 51.2 MB bf16
    short* wp      = (short*)(ws + o); o += (size_t)16 * 16384 * 2;               // 512 KB packed W
    int*   rowptr  = (int*)(ws + o);   o += (((size_t)(N_NODES + 1) * 4) + 15) & ~(size_t)15;
    int*   pos     = (int*)(ws + o);   o += (size_t)N_NODES * 4;
    int*   deg     = (int*)(ws + o);   o += (size_t)N_NODES * 4;
    int*   inc     = (int*)(ws + o);   o += (size_t)N_NODES * 4;
    int*   chunkS  = (int*)(ws + o);   o += 1024;
    int*   chunkO  = (int*)(ws + o);   o += 1024;
    int2*  cpack   = (int2*)(ws + o);  o += (size_t)N_EDGES * 8;                  // 25.6 MB

    const int nChunks = (N_NODES + SCAN_CHUNK - 1) / SCAN_CHUNK;   // 98

    // W pack + GEMM
    wpack_kernel<<<64, 256, 0, stream>>>(w, wp);
    gemm_mfma<<<(N_NODES + 63) / 64, 256, 0, stream>>>(x, wp, xwh);

    // CSR build
    zero_deg_kernel<<<(N_NODES + 255) / 256, 256, 0, stream>>>(deg);
    hist_kernel<<<2048, 256, 0, stream>>>(erow, deg);
    scan_part_kernel<<<nChunks, 256, 0, stream>>>(deg, inc, chunkS);
    scan_chunks_kernel<<<1, 128, 0, stream>>>(chunkS, chunkO, nChunks);
    scan_final_kernel<<<(N_NODES + 255) / 256, 256, 0, stream>>>(inc, chunkO, rowptr, pos);
    fill_csr_kernel<<<2048, 256, 0, stream>>>(erow, ecol, eval_, pos, cpack);

    // Aggregate + bias + relu
    aggregate_kernel<<<(N_NODES * 64) / 256, 256, 0, stream>>>(
        rowptr, cpack, reinterpret_cast<const ushort4*>(xwh), bias, out);
}